// Round 14
// baseline (152.449 us; speedup 1.0000x reference)
//
#include <hip/hip_runtime.h>
#include <stdint.h>

#define T_LEN 4096
#define C_DIM 1024
#define NH 16
#define CLOG2E 0.18033688011112042f   // 0.125 * log2(e)

typedef uint16_t u16;
typedef __attribute__((ext_vector_type(4))) float f32x4;
typedef __attribute__((ext_vector_type(8))) __bf16 bf16x8;
typedef __attribute__((ext_vector_type(8))) uint16_t u16x8;
typedef __attribute__((ext_vector_type(4))) float fvec4;

static __device__ __forceinline__ u16 f2b(float f) {
  union { float f; uint32_t u; } v; v.f = f;
  uint32_t u = v.u;
  return (u16)((u + 0x7fffu + ((u >> 16) & 1u)) >> 16);
}

static __device__ __forceinline__ float b2f(u16 b) {
  union { uint32_t u; float f; } v; v.u = ((uint32_t)b) << 16;
  return v.f;
}

// packed fp32->bf16x2 (RNE) — inline asm, no builtin on gfx950
static __device__ __forceinline__ uint32_t cvtpk(float lo, float hi) {
  uint32_t r;
  asm("v_cvt_pk_bf16_f32 %0, %1, %2" : "=v"(r) : "v"(lo), "v"(hi));
  return r;
}

static __device__ __forceinline__ f32x4 mfma16(u16x8 a, u16x8 b, f32x4 c) {
  return __builtin_amdgcn_mfma_f32_16x16x32_bf16(
      __builtin_bit_cast(bf16x8, a), __builtin_bit_cast(bf16x8, b), c, 0, 0, 0);
}

static __device__ __forceinline__ void gload_lds16(const void* g, void* l) {
  __builtin_amdgcn_global_load_lds(
      (const __attribute__((address_space(1))) uint32_t*)g,
      (__attribute__((address_space(3))) uint32_t*)l, 16, 0, 0);
}

// ---------------- merged fp32 -> bf16 cast (1 launch) ----------------
__global__ void cast_all(const float* __restrict__ x,
                         const float* __restrict__ wq, const float* __restrict__ wk,
                         const float* __restrict__ wv, const float* __restrict__ wp,
                         u16* __restrict__ xb,
                         u16* __restrict__ wqb, u16* __restrict__ wkb,
                         u16* __restrict__ wvb, u16* __restrict__ wpb) {
  int i = blockIdx.x * blockDim.x + threadIdx.x;
  if (i >= 131072) return;
  const int z = blockIdx.y;
  const float* in;
  u16* out;
  if (z < 4) {
    in  = (z == 0) ? wq  : (z == 1) ? wk  : (z == 2) ? wv  : wp;
    out = (z == 0) ? wqb : (z == 1) ? wkb : (z == 2) ? wvb : wpb;
  } else {
    in  = x  + (size_t)(z - 4) * 131072 * 8;
    out = xb + (size_t)(z - 4) * 131072 * 8;
  }
  const fvec4* p = (const fvec4*)(in + (size_t)i * 8);
  fvec4 a = p[0], b = p[1];
  u16x8 o;
  o[0] = f2b(a[0]); o[1] = f2b(a[1]); o[2] = f2b(a[2]); o[3] = f2b(a[3]);
  o[4] = f2b(b[0]); o[5] = f2b(b[1]); o[6] = f2b(b[2]); o[7] = f2b(b[3]);
  *(u16x8*)(out + (size_t)i * 8) = o;
}

// ---------------- QKV GEMM (m97 structure, unchanged) ----------------
__global__ __launch_bounds__(256) void gemm_qkv(
    const u16* __restrict__ xb,
    const u16* __restrict__ wqb, const u16* __restrict__ wkb, const u16* __restrict__ wvb,
    const float* __restrict__ bq, const float* __restrict__ bk, const float* __restrict__ bv,
    u16* __restrict__ qh, u16* __restrict__ kh, u16* __restrict__ vt)
{
  __shared__ u16 sA[128 * 32];
  __shared__ u16 sB[128 * 32];
  const int K = C_DIM;
  const int z = blockIdx.z;
  const u16* wb = (z == 0) ? wqb : (z == 1) ? wkb : wvb;
  const float* bias = (z == 0) ? bq : (z == 1) ? bk : bv;
  const int m0 = blockIdx.x * 128;
  const int n0 = blockIdx.y * 128;
  const int tid = threadIdx.x;
  const int lane = tid & 63;
  const int w = tid >> 6;
  const int wm = (w >> 1) * 64;
  const int wn = (w & 1) * 64;
  const int lr = lane & 15;
  const int lk = (lane >> 4) * 8;

  f32x4 acc[4][4];
#pragma unroll
  for (int m = 0; m < 4; ++m)
#pragma unroll
    for (int n = 0; n < 4; ++n) acc[m][n] = (f32x4){0.f, 0.f, 0.f, 0.f};

  const int srow = tid >> 2;
  const int scol = (tid & 3) * 8;
  const u16* gA = xb + (size_t)(m0 + srow) * K + scol;
  const u16* gB = wb + (size_t)(n0 + srow) * K + scol;

  for (int k0 = 0; k0 < K; k0 += 32) {
    gload_lds16(gA + k0,          &sA[tid * 8]);
    gload_lds16(gA + 64 * K + k0, &sA[2048 + tid * 8]);
    gload_lds16(gB + k0,          &sB[tid * 8]);
    gload_lds16(gB + 64 * K + k0, &sB[2048 + tid * 8]);
    __syncthreads();
    u16x8 af[4], bfr[4];
#pragma unroll
    for (int m = 0; m < 4; ++m) af[m]  = *(const u16x8*)&sA[(wm + m * 16 + lr) * 32 + lk];
#pragma unroll
    for (int n = 0; n < 4; ++n) bfr[n] = *(const u16x8*)&sB[(wn + n * 16 + lr) * 32 + lk];
#pragma unroll
    for (int m = 0; m < 4; ++m)
#pragma unroll
      for (int n = 0; n < 4; ++n) acc[m][n] = mfma16(af[m], bfr[n], acc[m][n]);
    __syncthreads();
  }

  const int lg = lane >> 4;
#pragma unroll
  for (int n = 0; n < 4; ++n) {
    const int o = n0 + wn + n * 16 + lr;
    const float bb = bias[o];
    const int h = o >> 6;
    const int d = o & 63;
#pragma unroll
    for (int m = 0; m < 4; ++m) {
      const int tb = m0 + wm + m * 16 + lg * 4;
      if (z == 2) {
        uint2 pk;
        pk.x = cvtpk(acc[m][n][0] + bb, acc[m][n][1] + bb);
        pk.y = cvtpk(acc[m][n][2] + bb, acc[m][n][3] + bb);
        *(uint2*)&vt[(size_t)o * T_LEN + tb] = pk;
      } else if (z == 0) {
#pragma unroll
        for (int r = 0; r < 4; ++r)
          qh[((size_t)h * T_LEN + tb + r) * 64 + d] = f2b((acc[m][n][r] + bb) * CLOG2E);
      } else {
#pragma unroll
        for (int r = 0; r < 4; ++r)
          kh[((size_t)h * T_LEN + tb + r) * 64 + d] = f2b(acc[m][n][r] + bb);
      }
    }
  }
}

// ---------------- output projection: 128x64 tiles (R11, unchanged) ----------------
__global__ __launch_bounds__(256) void gemm_proj(
    const u16* __restrict__ yb, const u16* __restrict__ wpb,
    const float* __restrict__ bp, float* __restrict__ out)
{
  __shared__ u16 sA[128 * 32];
  __shared__ u16 sB[64 * 32];
  const int K = C_DIM;
  const int m0 = blockIdx.x * 128;
  const int n0 = blockIdx.y * 64;
  const int tid = threadIdx.x;
  const int lane = tid & 63;
  const int w = tid >> 6;
  const int wm = w * 32;
  const int lr = lane & 15;
  const int lk = (lane >> 4) * 8;

  f32x4 acc[2][4];
#pragma unroll
  for (int m = 0; m < 2; ++m)
#pragma unroll
    for (int n = 0; n < 4; ++n) acc[m][n] = (f32x4){0.f, 0.f, 0.f, 0.f};

  const int srow = tid >> 2;
  const int scol = (tid & 3) * 8;
  const u16* gA = yb  + (size_t)(m0 + srow) * K + scol;
  const u16* gB = wpb + (size_t)(n0 + srow) * K + scol;

  for (int k0 = 0; k0 < K; k0 += 32) {
    gload_lds16(gA + k0,          &sA[tid * 8]);
    gload_lds16(gA + 64 * K + k0, &sA[2048 + tid * 8]);
    gload_lds16(gB + k0,          &sB[tid * 8]);
    __syncthreads();
    u16x8 af[2], bfr[4];
#pragma unroll
    for (int m = 0; m < 2; ++m) af[m]  = *(const u16x8*)&sA[(wm + m * 16 + lr) * 32 + lk];
#pragma unroll
    for (int n = 0; n < 4; ++n) bfr[n] = *(const u16x8*)&sB[(n * 16 + lr) * 32 + lk];
#pragma unroll
    for (int m = 0; m < 2; ++m)
#pragma unroll
      for (int n = 0; n < 4; ++n) acc[m][n] = mfma16(af[m], bfr[n], acc[m][n]);
    __syncthreads();
  }

  const int lg = lane >> 4;
#pragma unroll
  for (int n = 0; n < 4; ++n) {
    const int o = n0 + n * 16 + lr;
    const float bb = bp[o];
#pragma unroll
    for (int m = 0; m < 2; ++m) {
      const int tb = m0 + wm + m * 16 + lg * 4;
#pragma unroll
      for (int r = 0; r < 4; ++r)
        out[(size_t)(tb + r) * C_DIM + o] = acc[m][n][r] + bb;
    }
  }
}

// ---------------- flash attention v14: R12 inner loop, 28-tile chunks, no setprio --
// Chunking: (h,qb) split into ceil((qb+1)/28) chunks of <=28 kv-tiles.
//   qb<=27: 1 chunk (direct write). qb 28..55: 2 chunks. qb 56..63: 3 chunks.
// 1728 blocks (1024 resident + 704 queued -> dynamic backfill), XCD-chunked,
// long-chunks-first order. Partials (O bf16 + m/l f32) in the dead ws region.
// setprio REMOVED (m190: null-to-negative in 4-wave lockstep structures).
__global__ __launch_bounds__(256) void attn_kernel(
    const u16* __restrict__ qh, const u16* __restrict__ kh, const u16* __restrict__ vt,
    u16* __restrict__ y, u16* __restrict__ po, float* __restrict__ pml)
{
  __shared__ char skb[2][8192];
  __shared__ char svb[2][8192];
  __shared__ u16 pp[4][16][64];        // 8192 B, XOR-swizzled
  // bid -> (h, qb, chunk): xcd=bid&7 owns heads {2x,2x+1}; per-head i = (bid>>3)>>1:
  //  i<36: (qb=28+i, c0, len 28) | i<44: (qb=56+i-36, c1, len 28)
  //  i<72: single qb=27-(i-44) desc | i<100: (qb=55-(i-72), c1) desc | else (qb=63-(i-100), c2)
  const int bid = blockIdx.x;
  const int j = bid >> 3;                     // 0..215
  const int h = ((bid & 7) << 1) + (j & 1);
  const int i = j >> 1;                       // 0..107
  int qb, c;
  if (i < 36)       { qb = 28 + i;          c = 0; }
  else if (i < 44)  { qb = 56 + (i - 36);   c = 1; }
  else if (i < 72)  { qb = 27 - (i - 44);   c = 0; }
  else if (i < 100) { qb = 55 - (i - 72);   c = 1; }
  else              { qb = 63 - (i - 100);  c = 2; }
  const int t0 = c * 28;
  const int t1e = 28 * (c + 1);
  const int t1 = (t1e < qb + 1) ? t1e : (qb + 1);
  const bool direct = (qb <= 27);

  const int tid = threadIdx.x;
  const int lane = tid & 63;
  const int w = tid >> 6;
  const int lr = lane & 15;
  const int lg = lane >> 4;
  const int sw = (lr & 7) << 4;
  const int qt0 = qb * 64 + w * 16;

  const int srow = tid >> 2;
  const int scb = (tid & 3) * 32;
  const int wo0 = srow * 128 + (scb ^ ((srow & 7) << 4));
  const int wo1 = srow * 128 + ((scb + 16) ^ ((srow & 7) << 4));
  const u16* gkbase = kh + ((size_t)h * T_LEN + srow) * 64 + (tid & 3) * 16;
  const u16* gvbase = vt + ((size_t)h * 64 + srow) * T_LEN + (tid & 3) * 16;
  char* ppb = (char*)&pp[w][0][0];

  const u16* qbase = qh + ((size_t)h * T_LEN + qt0 + lr) * 64 + lg * 8;
  u16x8 qf0 = *(const u16x8*)(qbase);
  u16x8 qf1 = *(const u16x8*)(qbase + 32);

  f32x4 oacc[4];
#pragma unroll
  for (int i2 = 0; i2 < 4; ++i2) oacc[i2] = (f32x4){0.f, 0.f, 0.f, 0.f};
  float mrow = -1e30f, lsum = 0.f;

  u16x8 ka = *(const u16x8*)(gkbase + (size_t)t0 * 4096);
  u16x8 kb = *(const u16x8*)(gkbase + (size_t)t0 * 4096 + 8);
  u16x8 va = *(const u16x8*)(gvbase + t0 * 64);
  u16x8 vb = *(const u16x8*)(gvbase + t0 * 64 + 8);
  *(u16x8*)(skb[0] + wo0) = ka; *(u16x8*)(skb[0] + wo1) = kb;
  *(u16x8*)(svb[0] + wo0) = va; *(u16x8*)(svb[0] + wo1) = vb;
  int cur = 0;

  for (int t = t0; t < t1; ++t) {
    __syncthreads();   // buffer[cur] writes visible
    if (t + 1 < t1) {  // issue next-tile loads; latency spans this tile's compute
      const size_t ko = (size_t)(t + 1) * 4096;
      ka = *(const u16x8*)(gkbase + ko);
      kb = *(const u16x8*)(gkbase + ko + 8);
      va = *(const u16x8*)(gvbase + (t + 1) * 64);
      vb = *(const u16x8*)(gvbase + (t + 1) * 64 + 8);
    }
    const char* skc = skb[cur];
    const char* svc = svb[cur];

    // S^T = K * Q^T  (scale folded into Q)
    f32x4 sacc[4];
#pragma unroll
    for (int i2 = 0; i2 < 4; ++i2) {
      const int ro = (i2 * 16 + lr) * 128;
      u16x8 a0 = *(const u16x8*)(skc + ro + ((lg * 16) ^ sw));
      u16x8 a1 = *(const u16x8*)(skc + ro + ((lg * 16 + 64) ^ sw));
      f32x4 zz = (f32x4){0.f, 0.f, 0.f, 0.f};
      zz = mfma16(a0, qf0, zz);
      zz = mfma16(a1, qf1, zz);
      sacc[i2] = zz;
    }

    // mask in place on the diagonal tile only (reached only in the last chunk)
    if (t == qb) {
      const int qg = qt0 + lr;
      const int kt0 = t * 64;
#pragma unroll
      for (int i2 = 0; i2 < 4; ++i2)
#pragma unroll
        for (int r = 0; r < 4; ++r) {
          const int kt = kt0 + i2 * 16 + lg * 4 + r;
          sacc[i2][r] = (kt <= qg) ? sacc[i2][r] : -1e30f;
        }
    }
    float x0 = fmaxf(fmaxf(sacc[0][0], sacc[0][1]), sacc[0][2]);
    float x1 = fmaxf(fmaxf(sacc[0][3], sacc[1][0]), sacc[1][1]);
    float x2 = fmaxf(fmaxf(sacc[1][2], sacc[1][3]), sacc[2][0]);
    float x3 = fmaxf(fmaxf(sacc[2][1], sacc[2][2]), sacc[2][3]);
    float x4 = fmaxf(fmaxf(sacc[3][0], sacc[3][1]), sacc[3][2]);
    float pm = fmaxf(fmaxf(fmaxf(x0, x1), fmaxf(x2, x3)), fmaxf(x4, sacc[3][3]));

    if (!__all(pm <= mrow)) {          // defer-max vote (mrow row-uniform)
      float pmf = fmaxf(pm, __shfl_xor(pm, 16));
      pmf = fmaxf(pmf, __shfl_xor(pmf, 32));
      const float mnew = fmaxf(mrow, pmf);
      const float sc = exp2f(mrow - mnew);
      lsum *= sc;
#pragma unroll
      for (int i2 = 0; i2 < 4; ++i2) oacc[i2] *= sc;
      mrow = mnew;
    }

    float u0 = 0.f, u1 = 0.f, u2 = 0.f, u3 = 0.f;
#pragma unroll
    for (int i2 = 0; i2 < 4; ++i2) {
      float e0 = exp2f(sacc[i2][0] - mrow);
      float e1 = exp2f(sacc[i2][1] - mrow);
      float e2 = exp2f(sacc[i2][2] - mrow);
      float e3 = exp2f(sacc[i2][3] - mrow);
      u0 += e0; u1 += e1; u2 += e2; u3 += e3;
      uint2 pk;
      pk.x = cvtpk(e0, e1);
      pk.y = cvtpk(e2, e3);
      *(uint2*)(ppb + ((lr * 128 + i2 * 32 + lg * 8) ^ sw)) = pk;
    }
    lsum += (u0 + u1) + (u2 + u3);

    // O^T += V^T * P^T
#pragma unroll
    for (int ks = 0; ks < 2; ++ks) {
      u16x8 pf = *(const u16x8*)(ppb + ((lr * 128 + lg * 16 + ks * 64) ^ sw));
#pragma unroll
      for (int dblk = 0; dblk < 4; ++dblk) {
        const int ro = (dblk * 16 + lr) * 128;
        u16x8 vf = *(const u16x8*)(svc + ro + ((lg * 16 + ks * 64) ^ sw));
        oacc[dblk] = mfma16(vf, pf, oacc[dblk]);
      }
    }

    if (t + 1 < t1) {
      char* dk = skb[cur ^ 1];
      char* dv = svb[cur ^ 1];
      *(u16x8*)(dk + wo0) = ka; *(u16x8*)(dk + wo1) = kb;
      *(u16x8*)(dv + wo0) = va; *(u16x8*)(dv + wo1) = vb;
    }
    cur ^= 1;
  }

  lsum += __shfl_xor(lsum, 16);
  lsum += __shfl_xor(lsum, 32);

  if (direct) {
    const float inv = 1.0f / lsum;
#pragma unroll
    for (int dblk = 0; dblk < 4; ++dblk) {
      uint2 pk;
      pk.x = cvtpk(oacc[dblk][0] * inv, oacc[dblk][1] * inv);
      pk.y = cvtpk(oacc[dblk][2] * inv, oacc[dblk][3] * inv);
      *(uint2*)&y[(size_t)(qt0 + lr) * C_DIM + h * 64 + dblk * 16 + lg * 4] = pk;
    }
  } else {
    // slot map: qb 28..55 -> (qb-28)*2 (+c of 2); qb 56..63 -> 56+(qb-56)*3 (+c of 3)
    const int sb = (qb <= 55) ? (qb - 28) * 2 : 56 + (qb - 56) * 3;
    const int slot = h * 80 + sb + c;
    u16* pob = po + (size_t)slot * 4096 + (size_t)(w * 16 + lr) * 64;
#pragma unroll
    for (int dblk = 0; dblk < 4; ++dblk) {
      uint2 pk;
      pk.x = cvtpk(oacc[dblk][0], oacc[dblk][1]);
      pk.y = cvtpk(oacc[dblk][2], oacc[dblk][3]);
      *(uint2*)(pob + dblk * 16 + lg * 4) = pk;
    }
    if (lg == 0) {
      float2* pm2 = (float2*)pml;
      pm2[slot * 64 + w * 16 + lr] = make_float2(mrow, lsum);
    }
  }
}

// ---------------- partial combine: 576 blocks = 16 heads x (qb 28..63) ----------------
__global__ __launch_bounds__(256) void attn_combine(
    const u16* __restrict__ po, const float* __restrict__ pml, u16* __restrict__ y)
{
  const int bid = blockIdx.x;            // 0..575
  const int h = bid / 36;
  const int qi = bid - h * 36;
  const int qb = 28 + qi;
  const int nch = (qb <= 55) ? 2 : 3;
  const int sb = (qb <= 55) ? (qb - 28) * 2 : 56 + (qb - 56) * 3;
  const int slot0 = h * 80 + sb;
  const int tid = threadIdx.x;
  const int row = tid >> 2;              // 0..63
  const int dseg = (tid & 3) * 16;
  const float2* pm2 = (const float2*)pml;

  float2 ml0 = pm2[(slot0 + 0) * 64 + row];
  float2 ml1 = pm2[(slot0 + 1) * 64 + row];
  float2 ml2 = make_float2(-1e30f, 0.f);
  float m = fmaxf(ml0.x, ml1.x);
  if (nch == 3) { ml2 = pm2[(slot0 + 2) * 64 + row]; m = fmaxf(m, ml2.x); }
  const float f0 = exp2f(ml0.x - m);
  const float f1 = exp2f(ml1.x - m);
  const float f2 = (nch == 3) ? exp2f(ml2.x - m) : 0.f;
  const float L = ml0.y * f0 + ml1.y * f1 + ml2.y * f2;
  const float inv = 1.0f / L;
  const float g0 = f0 * inv, g1 = f1 * inv, g2 = f2 * inv;

  float acc[16];
#pragma unroll
  for (int e = 0; e < 16; ++e) acc[e] = 0.f;
  for (int cc = 0; cc < nch; ++cc) {
    const float g = (cc == 0) ? g0 : (cc == 1) ? g1 : g2;
    const u16* p = po + (size_t)(slot0 + cc) * 4096 + row * 64 + dseg;
    u16x8 a0 = *(const u16x8*)(p);
    u16x8 a1 = *(const u16x8*)(p + 8);
#pragma unroll
    for (int e = 0; e < 8; ++e) acc[e]     += b2f(a0[e]) * g;
#pragma unroll
    for (int e = 0; e < 8; ++e) acc[8 + e] += b2f(a1[e]) * g;
  }
  uint4 o0, o1;
  o0.x = cvtpk(acc[0], acc[1]);   o0.y = cvtpk(acc[2], acc[3]);
  o0.z = cvtpk(acc[4], acc[5]);   o0.w = cvtpk(acc[6], acc[7]);
  o1.x = cvtpk(acc[8], acc[9]);   o1.y = cvtpk(acc[10], acc[11]);
  o1.z = cvtpk(acc[12], acc[13]); o1.w = cvtpk(acc[14], acc[15]);
  u16* yp = y + (size_t)(qb * 64 + row) * C_DIM + h * 64 + dseg;
  *(uint4*)(yp) = o0;
  *(uint4*)(yp + 8) = o1;
}

extern "C" void kernel_launch(void* const* d_in, const int* in_sizes, int n_in,
                              void* d_out, int out_size, void* d_ws, size_t ws_size,
                              hipStream_t stream) {
  const float* x  = (const float*)d_in[0];
  const float* wq = (const float*)d_in[1];
  const float* bq = (const float*)d_in[2];
  const float* wk = (const float*)d_in[3];
  const float* bk = (const float*)d_in[4];
  const float* wv = (const float*)d_in[5];
  const float* bv = (const float*)d_in[6];
  const float* wp = (const float*)d_in[7];
  const float* bp = (const float*)d_in[8];

  char* ws = (char*)d_ws;
  const size_t MB = 1024 * 1024;
  u16* xb  = (u16*)(ws + 0 * MB);
  u16* wqb = (u16*)(ws + 8 * MB);
  u16* wkb = (u16*)(ws + 10 * MB);
  u16* wvb = (u16*)(ws + 12 * MB);
  u16* wpb = (u16*)(ws + 14 * MB);
  u16* qh  = (u16*)(ws + 16 * MB);
  u16* kh  = (u16*)(ws + 24 * MB);
  u16* vt  = (u16*)(ws + 32 * MB);
  u16* y   = (u16*)(ws + 40 * MB);
  // partials reuse the region dead after gemm_qkv (xb/wqb/wkb):
  u16*   po  = (u16*)(ws + 0 * MB);    // 1280 slots x 64 rows x 64 d bf16 = 10.5 MB
  float* pml = (float*)(ws + 11 * MB); // 1280 slots x 64 rows x {m,l} f32 = 0.66 MB

  cast_all<<<dim3(512, 8), dim3(256), 0, stream>>>(
      x, wq, wk, wv, wp, xb, wqb, wkb, wvb, wpb);

  gemm_qkv<<<dim3(32, 8, 3), dim3(256), 0, stream>>>(
      xb, wqb, wkb, wvb, bq, bk, bv, qh, kh, vt);

  attn_kernel<<<dim3(1728), dim3(256), 0, stream>>>(qh, kh, vt, y, po, pml);

  attn_combine<<<dim3(576), dim3(256), 0, stream>>>(po, pml, y);

  gemm_proj<<<dim3(32, 16), dim3(256), 0, stream>>>(y, wpb, bp, (float*)d_out);
}

// Round 15
// 144.089 us; speedup vs baseline: 1.0580x; 1.0580x over previous
//
#include <hip/hip_runtime.h>
#include <stdint.h>

#define T_LEN 4096
#define C_DIM 1024
#define NH 16
#define CLOG2E 0.18033688011112042f   // 0.125 * log2(e)

typedef uint16_t u16;
typedef __attribute__((ext_vector_type(4))) float f32x4;
typedef __attribute__((ext_vector_type(8))) __bf16 bf16x8;
typedef __attribute__((ext_vector_type(8))) uint16_t u16x8;
typedef __attribute__((ext_vector_type(4))) float fvec4;

static __device__ __forceinline__ u16 f2b(float f) {
  union { float f; uint32_t u; } v; v.f = f;
  uint32_t u = v.u;
  return (u16)((u + 0x7fffu + ((u >> 16) & 1u)) >> 16);
}

static __device__ __forceinline__ float b2f(u16 b) {
  union { uint32_t u; float f; } v; v.u = ((uint32_t)b) << 16;
  return v.f;
}

// packed fp32->bf16x2 (RNE) — inline asm, no builtin on gfx950
static __device__ __forceinline__ uint32_t cvtpk(float lo, float hi) {
  uint32_t r;
  asm("v_cvt_pk_bf16_f32 %0, %1, %2" : "=v"(r) : "v"(lo), "v"(hi));
  return r;
}

static __device__ __forceinline__ f32x4 mfma16(u16x8 a, u16x8 b, f32x4 c) {
  return __builtin_amdgcn_mfma_f32_16x16x32_bf16(
      __builtin_bit_cast(bf16x8, a), __builtin_bit_cast(bf16x8, b), c, 0, 0, 0);
}

static __device__ __forceinline__ void gload_lds16(const void* g, void* l) {
  __builtin_amdgcn_global_load_lds(
      (const __attribute__((address_space(1))) uint32_t*)g,
      (__attribute__((address_space(3))) uint32_t*)l, 16, 0, 0);
}

// ---------------- merged fp32 -> bf16 cast (1 launch) ----------------
__global__ void cast_all(const float* __restrict__ x,
                         const float* __restrict__ wq, const float* __restrict__ wk,
                         const float* __restrict__ wv, const float* __restrict__ wp,
                         u16* __restrict__ xb,
                         u16* __restrict__ wqb, u16* __restrict__ wkb,
                         u16* __restrict__ wvb, u16* __restrict__ wpb) {
  int i = blockIdx.x * blockDim.x + threadIdx.x;
  if (i >= 131072) return;
  const int z = blockIdx.y;
  const float* in;
  u16* out;
  if (z < 4) {
    in  = (z == 0) ? wq  : (z == 1) ? wk  : (z == 2) ? wv  : wp;
    out = (z == 0) ? wqb : (z == 1) ? wkb : (z == 2) ? wvb : wpb;
  } else {
    in  = x  + (size_t)(z - 4) * 131072 * 8;
    out = xb + (size_t)(z - 4) * 131072 * 8;
  }
  const fvec4* p = (const fvec4*)(in + (size_t)i * 8);
  fvec4 a = p[0], b = p[1];
  u16x8 o;
  o[0] = f2b(a[0]); o[1] = f2b(a[1]); o[2] = f2b(a[2]); o[3] = f2b(a[3]);
  o[4] = f2b(b[0]); o[5] = f2b(b[1]); o[6] = f2b(b[2]); o[7] = f2b(b[3]);
  *(u16x8*)(out + (size_t)i * 8) = o;
}

// ---------------- QKV GEMM (m97 structure) ----------------
__global__ __launch_bounds__(256) void gemm_qkv(
    const u16* __restrict__ xb,
    const u16* __restrict__ wqb, const u16* __restrict__ wkb, const u16* __restrict__ wvb,
    const float* __restrict__ bq, const float* __restrict__ bk, const float* __restrict__ bv,
    u16* __restrict__ qh, u16* __restrict__ kh, u16* __restrict__ vt)
{
  __shared__ u16 sA[128 * 32];
  __shared__ u16 sB[128 * 32];
  const int K = C_DIM;
  const int z = blockIdx.z;
  const u16* wb = (z == 0) ? wqb : (z == 1) ? wkb : wvb;
  const float* bias = (z == 0) ? bq : (z == 1) ? bk : bv;
  const int m0 = blockIdx.x * 128;
  const int n0 = blockIdx.y * 128;
  const int tid = threadIdx.x;
  const int lane = tid & 63;
  const int w = tid >> 6;
  const int wm = (w >> 1) * 64;
  const int wn = (w & 1) * 64;
  const int lr = lane & 15;
  const int lk = (lane >> 4) * 8;

  f32x4 acc[4][4];
#pragma unroll
  for (int m = 0; m < 4; ++m)
#pragma unroll
    for (int n = 0; n < 4; ++n) acc[m][n] = (f32x4){0.f, 0.f, 0.f, 0.f};

  const int srow = tid >> 2;
  const int scol = (tid & 3) * 8;
  const u16* gA = xb + (size_t)(m0 + srow) * K + scol;
  const u16* gB = wb + (size_t)(n0 + srow) * K + scol;

  for (int k0 = 0; k0 < K; k0 += 32) {
    gload_lds16(gA + k0,          &sA[tid * 8]);
    gload_lds16(gA + 64 * K + k0, &sA[2048 + tid * 8]);
    gload_lds16(gB + k0,          &sB[tid * 8]);
    gload_lds16(gB + 64 * K + k0, &sB[2048 + tid * 8]);
    __syncthreads();
    u16x8 af[4], bfr[4];
#pragma unroll
    for (int m = 0; m < 4; ++m) af[m]  = *(const u16x8*)&sA[(wm + m * 16 + lr) * 32 + lk];
#pragma unroll
    for (int n = 0; n < 4; ++n) bfr[n] = *(const u16x8*)&sB[(wn + n * 16 + lr) * 32 + lk];
#pragma unroll
    for (int m = 0; m < 4; ++m)
#pragma unroll
      for (int n = 0; n < 4; ++n) acc[m][n] = mfma16(af[m], bfr[n], acc[m][n]);
    __syncthreads();
  }

  const int lg = lane >> 4;
#pragma unroll
  for (int n = 0; n < 4; ++n) {
    const int o = n0 + wn + n * 16 + lr;
    const float bb = bias[o];
    const int h = o >> 6;
    const int d = o & 63;
#pragma unroll
    for (int m = 0; m < 4; ++m) {
      const int tb = m0 + wm + m * 16 + lg * 4;
      if (z == 2) {
        uint2 pk;
        pk.x = cvtpk(acc[m][n][0] + bb, acc[m][n][1] + bb);
        pk.y = cvtpk(acc[m][n][2] + bb, acc[m][n][3] + bb);
        *(uint2*)&vt[(size_t)o * T_LEN + tb] = pk;
      } else if (z == 0) {
#pragma unroll
        for (int r = 0; r < 4; ++r)
          qh[((size_t)h * T_LEN + tb + r) * 64 + d] = f2b((acc[m][n][r] + bb) * CLOG2E);
      } else {
#pragma unroll
        for (int r = 0; r < 4; ++r)
          kh[((size_t)h * T_LEN + tb + r) * 64 + d] = f2b(acc[m][n][r] + bb);
      }
    }
  }
}

// ---------------- output projection: 128x64 tiles ----------------
__global__ __launch_bounds__(256) void gemm_proj(
    const u16* __restrict__ yb, const u16* __restrict__ wpb,
    const float* __restrict__ bp, float* __restrict__ out)
{
  __shared__ u16 sA[128 * 32];
  __shared__ u16 sB[64 * 32];
  const int K = C_DIM;
  const int m0 = blockIdx.x * 128;
  const int n0 = blockIdx.y * 64;
  const int tid = threadIdx.x;
  const int lane = tid & 63;
  const int w = tid >> 6;
  const int wm = w * 32;
  const int lr = lane & 15;
  const int lk = (lane >> 4) * 8;

  f32x4 acc[2][4];
#pragma unroll
  for (int m = 0; m < 2; ++m)
#pragma unroll
    for (int n = 0; n < 4; ++n) acc[m][n] = (f32x4){0.f, 0.f, 0.f, 0.f};

  const int srow = tid >> 2;
  const int scol = (tid & 3) * 8;
  const u16* gA = yb  + (size_t)(m0 + srow) * K + scol;
  const u16* gB = wpb + (size_t)(n0 + srow) * K + scol;

  for (int k0 = 0; k0 < K; k0 += 32) {
    gload_lds16(gA + k0,          &sA[tid * 8]);
    gload_lds16(gA + 64 * K + k0, &sA[2048 + tid * 8]);
    gload_lds16(gB + k0,          &sB[tid * 8]);
    __syncthreads();
    u16x8 af[2], bfr[4];
#pragma unroll
    for (int m = 0; m < 2; ++m) af[m]  = *(const u16x8*)&sA[(wm + m * 16 + lr) * 32 + lk];
#pragma unroll
    for (int n = 0; n < 4; ++n) bfr[n] = *(const u16x8*)&sB[(n * 16 + lr) * 32 + lk];
#pragma unroll
    for (int m = 0; m < 2; ++m)
#pragma unroll
      for (int n = 0; n < 4; ++n) acc[m][n] = mfma16(af[m], bfr[n], acc[m][n]);
    __syncthreads();
  }

  const int lg = lane >> 4;
#pragma unroll
  for (int n = 0; n < 4; ++n) {
    const int o = n0 + n * 16 + lr;
    const float bb = bp[o];
#pragma unroll
    for (int m = 0; m < 2; ++m) {
      const int tb = m0 + wm + m * 16 + lg * 4;
#pragma unroll
      for (int r = 0; r < 4; ++r)
        out[(size_t)(tb + r) * C_DIM + o] = acc[m][n][r] + bb;
    }
  }
}

// ---------------- flash attention (R12 config: split-K 2-way, best measured) -----
__global__ __launch_bounds__(256) void attn_kernel(
    const u16* __restrict__ qh, const u16* __restrict__ kh, const u16* __restrict__ vt,
    u16* __restrict__ y, u16* __restrict__ po, float* __restrict__ pml)
{
  __shared__ char skb[2][8192];
  __shared__ char svb[2][8192];
  __shared__ u16 pp[4][16][64];        // 8192 B, XOR-swizzled
  const int bid = blockIdx.x;
  const int j = bid >> 3;                     // 0..191
  const int h = ((bid & 7) << 1) + (j & 1);
  const int i = j >> 1;                       // 0..95
  int qb, c0;
  if (i < 32) { qb = 32 + i; c0 = 0; }
  else {
    const int k = (i - 32) >> 1;
    if (((i - 32) & 1) == 0) { qb = 63 - k; c0 = 1; }
    else                     { qb = 31 - k; c0 = -1; }
  }
  const int t0 = (c0 == 1) ? 32 : 0;
  const int t1 = (c0 == 0) ? 32 : (qb + 1);
  const bool hasdiag = (c0 != 0);

  const int tid = threadIdx.x;
  const int lane = tid & 63;
  const int w = tid >> 6;
  const int lr = lane & 15;
  const int lg = lane >> 4;
  const int sw = (lr & 7) << 4;
  const int qt0 = qb * 64 + w * 16;

  const int srow = tid >> 2;
  const int scb = (tid & 3) * 32;
  const int wo0 = srow * 128 + (scb ^ ((srow & 7) << 4));
  const int wo1 = srow * 128 + ((scb + 16) ^ ((srow & 7) << 4));
  const u16* gkbase = kh + ((size_t)h * T_LEN + srow) * 64 + (tid & 3) * 16;
  const u16* gvbase = vt + ((size_t)h * 64 + srow) * T_LEN + (tid & 3) * 16;
  char* ppb = (char*)&pp[w][0][0];

  const u16* qbase = qh + ((size_t)h * T_LEN + qt0 + lr) * 64 + lg * 8;
  u16x8 qf0 = *(const u16x8*)(qbase);
  u16x8 qf1 = *(const u16x8*)(qbase + 32);

  f32x4 oacc[4];
#pragma unroll
  for (int i2 = 0; i2 < 4; ++i2) oacc[i2] = (f32x4){0.f, 0.f, 0.f, 0.f};
  float mrow = -1e30f, lsum = 0.f;

  u16x8 ka = *(const u16x8*)(gkbase + (size_t)t0 * 4096);
  u16x8 kb = *(const u16x8*)(gkbase + (size_t)t0 * 4096 + 8);
  u16x8 va = *(const u16x8*)(gvbase + t0 * 64);
  u16x8 vb = *(const u16x8*)(gvbase + t0 * 64 + 8);
  *(u16x8*)(skb[0] + wo0) = ka; *(u16x8*)(skb[0] + wo1) = kb;
  *(u16x8*)(svb[0] + wo0) = va; *(u16x8*)(svb[0] + wo1) = vb;
  int cur = 0;

  for (int t = t0; t < t1; ++t) {
    __syncthreads();   // buffer[cur] writes visible
    if (t + 1 < t1) {
      const size_t ko = (size_t)(t + 1) * 4096;
      ka = *(const u16x8*)(gkbase + ko);
      kb = *(const u16x8*)(gkbase + ko + 8);
      va = *(const u16x8*)(gvbase + (t + 1) * 64);
      vb = *(const u16x8*)(gvbase + (t + 1) * 64 + 8);
    }
    const char* skc = skb[cur];
    const char* svc = svb[cur];

    // S^T = K * Q^T  (scale folded into Q)
    f32x4 sacc[4];
    __builtin_amdgcn_s_setprio(1);
#pragma unroll
    for (int i2 = 0; i2 < 4; ++i2) {
      const int ro = (i2 * 16 + lr) * 128;
      u16x8 a0 = *(const u16x8*)(skc + ro + ((lg * 16) ^ sw));
      u16x8 a1 = *(const u16x8*)(skc + ro + ((lg * 16 + 64) ^ sw));
      f32x4 zz = (f32x4){0.f, 0.f, 0.f, 0.f};
      zz = mfma16(a0, qf0, zz);
      zz = mfma16(a1, qf1, zz);
      sacc[i2] = zz;
    }
    __builtin_amdgcn_s_setprio(0);

    // mask in place on the diagonal tile only
    if (hasdiag && t == qb) {
      const int qg = qt0 + lr;
      const int kt0 = t * 64;
#pragma unroll
      for (int i2 = 0; i2 < 4; ++i2)
#pragma unroll
        for (int r = 0; r < 4; ++r) {
          const int kt = kt0 + i2 * 16 + lg * 4 + r;
          sacc[i2][r] = (kt <= qg) ? sacc[i2][r] : -1e30f;
        }
    }
    float x0 = fmaxf(fmaxf(sacc[0][0], sacc[0][1]), sacc[0][2]);
    float x1 = fmaxf(fmaxf(sacc[0][3], sacc[1][0]), sacc[1][1]);
    float x2 = fmaxf(fmaxf(sacc[1][2], sacc[1][3]), sacc[2][0]);
    float x3 = fmaxf(fmaxf(sacc[2][1], sacc[2][2]), sacc[2][3]);
    float x4 = fmaxf(fmaxf(sacc[3][0], sacc[3][1]), sacc[3][2]);
    float pm = fmaxf(fmaxf(fmaxf(x0, x1), fmaxf(x2, x3)), fmaxf(x4, sacc[3][3]));

    if (!__all(pm <= mrow)) {
      float pmf = fmaxf(pm, __shfl_xor(pm, 16));
      pmf = fmaxf(pmf, __shfl_xor(pmf, 32));
      const float mnew = fmaxf(mrow, pmf);
      const float sc = exp2f(mrow - mnew);
      lsum *= sc;
#pragma unroll
      for (int i2 = 0; i2 < 4; ++i2) oacc[i2] *= sc;
      mrow = mnew;
    }

    float u0 = 0.f, u1 = 0.f, u2 = 0.f, u3 = 0.f;
#pragma unroll
    for (int i2 = 0; i2 < 4; ++i2) {
      float e0 = exp2f(sacc[i2][0] - mrow);
      float e1 = exp2f(sacc[i2][1] - mrow);
      float e2 = exp2f(sacc[i2][2] - mrow);
      float e3 = exp2f(sacc[i2][3] - mrow);
      u0 += e0; u1 += e1; u2 += e2; u3 += e3;
      uint2 pk;
      pk.x = cvtpk(e0, e1);
      pk.y = cvtpk(e2, e3);
      *(uint2*)(ppb + ((lr * 128 + i2 * 32 + lg * 8) ^ sw)) = pk;
    }
    lsum += (u0 + u1) + (u2 + u3);

    __builtin_amdgcn_s_setprio(1);
#pragma unroll
    for (int ks = 0; ks < 2; ++ks) {
      u16x8 pf = *(const u16x8*)(ppb + ((lr * 128 + lg * 16 + ks * 64) ^ sw));
#pragma unroll
      for (int dblk = 0; dblk < 4; ++dblk) {
        const int ro = (dblk * 16 + lr) * 128;
        u16x8 vf = *(const u16x8*)(svc + ro + ((lg * 16 + ks * 64) ^ sw));
        oacc[dblk] = mfma16(vf, pf, oacc[dblk]);
      }
    }
    __builtin_amdgcn_s_setprio(0);

    if (t + 1 < t1) {
      char* dk = skb[cur ^ 1];
      char* dv = svb[cur ^ 1];
      *(u16x8*)(dk + wo0) = ka; *(u16x8*)(dk + wo1) = kb;
      *(u16x8*)(dv + wo0) = va; *(u16x8*)(dv + wo1) = vb;
    }
    cur ^= 1;
  }

  lsum += __shfl_xor(lsum, 16);
  lsum += __shfl_xor(lsum, 32);

  if (c0 < 0) {
    const float inv = 1.0f / lsum;
#pragma unroll
    for (int dblk = 0; dblk < 4; ++dblk) {
      uint2 pk;
      pk.x = cvtpk(oacc[dblk][0] * inv, oacc[dblk][1] * inv);
      pk.y = cvtpk(oacc[dblk][2] * inv, oacc[dblk][3] * inv);
      *(uint2*)&y[(size_t)(qt0 + lr) * C_DIM + h * 64 + dblk * 16 + lg * 4] = pk;
    }
  } else {
    const int slot = (((h << 5) + (qb - 32)) << 1) + c0;
    u16* pob = po + (size_t)slot * 4096 + (size_t)(w * 16 + lr) * 64;
#pragma unroll
    for (int dblk = 0; dblk < 4; ++dblk) {
      uint2 pk;
      pk.x = cvtpk(oacc[dblk][0], oacc[dblk][1]);
      pk.y = cvtpk(oacc[dblk][2], oacc[dblk][3]);
      *(uint2*)(pob + dblk * 16 + lg * 4) = pk;
    }
    if (lg == 0) {
      float2* pm2 = (float2*)pml;
      pm2[slot * 64 + w * 16 + lr] = make_float2(mrow, lsum);
    }
  }
}

// ---------------- partial combine: 512 blocks (h, qb>=32), 256 thr ----------------
__global__ __launch_bounds__(256) void attn_combine(
    const u16* __restrict__ po, const float* __restrict__ pml, u16* __restrict__ y)
{
  const int bid = blockIdx.x;            // 0..511
  const int h = bid >> 5;
  const int q5 = bid & 31;
  const int tid = threadIdx.x;
  const int row = tid >> 2;
  const int dseg = (tid & 3) * 16;
  const int slot0 = (((h << 5) + q5) << 1);
  const float2 ml0 = ((const float2*)pml)[slot0 * 64 + row];
  const float2 ml1 = ((const float2*)pml)[(slot0 + 1) * 64 + row];
  const float m = fmaxf(ml0.x, ml1.x);
  const float f0 = exp2f(ml0.x - m);
  const float f1 = exp2f(ml1.x - m);
  const float inv = 1.0f / (ml0.y * f0 + ml1.y * f1);
  const float g0 = f0 * inv, g1 = f1 * inv;
  const u16* p0 = po + (size_t)slot0 * 4096 + row * 64 + dseg;
  const u16* p1 = p0 + 4096;
  u16x8 a0 = *(const u16x8*)(p0);
  u16x8 a1 = *(const u16x8*)(p0 + 8);
  u16x8 b0 = *(const u16x8*)(p1);
  u16x8 b1 = *(const u16x8*)(p1 + 8);
  uint4 o0, o1;
  float r0, r1;
  r0 = b2f(a0[0]) * g0 + b2f(b0[0]) * g1; r1 = b2f(a0[1]) * g0 + b2f(b0[1]) * g1;
  o0.x = cvtpk(r0, r1);
  r0 = b2f(a0[2]) * g0 + b2f(b0[2]) * g1; r1 = b2f(a0[3]) * g0 + b2f(b0[3]) * g1;
  o0.y = cvtpk(r0, r1);
  r0 = b2f(a0[4]) * g0 + b2f(b0[4]) * g1; r1 = b2f(a0[5]) * g0 + b2f(b0[5]) * g1;
  o0.z = cvtpk(r0, r1);
  r0 = b2f(a0[6]) * g0 + b2f(b0[6]) * g1; r1 = b2f(a0[7]) * g0 + b2f(b0[7]) * g1;
  o0.w = cvtpk(r0, r1);
  r0 = b2f(a1[0]) * g0 + b2f(b1[0]) * g1; r1 = b2f(a1[1]) * g0 + b2f(b1[1]) * g1;
  o1.x = cvtpk(r0, r1);
  r0 = b2f(a1[2]) * g0 + b2f(b1[2]) * g1; r1 = b2f(a1[3]) * g0 + b2f(b1[3]) * g1;
  o1.y = cvtpk(r0, r1);
  r0 = b2f(a1[4]) * g0 + b2f(b1[4]) * g1; r1 = b2f(a1[5]) * g0 + b2f(b1[5]) * g1;
  o1.z = cvtpk(r0, r1);
  r0 = b2f(a1[6]) * g0 + b2f(b1[6]) * g1; r1 = b2f(a1[7]) * g0 + b2f(b1[7]) * g1;
  o1.w = cvtpk(r0, r1);
  u16* yp = y + (size_t)((q5 + 32) * 64 + row) * C_DIM + h * 64 + dseg;
  *(uint4*)(yp) = o0;
  *(uint4*)(yp + 8) = o1;
}

extern "C" void kernel_launch(void* const* d_in, const int* in_sizes, int n_in,
                              void* d_out, int out_size, void* d_ws, size_t ws_size,
                              hipStream_t stream) {
  const float* x  = (const float*)d_in[0];
  const float* wq = (const float*)d_in[1];
  const float* bq = (const float*)d_in[2];
  const float* wk = (const float*)d_in[3];
  const float* bk = (const float*)d_in[4];
  const float* wv = (const float*)d_in[5];
  const float* bv = (const float*)d_in[6];
  const float* wp = (const float*)d_in[7];
  const float* bp = (const float*)d_in[8];

  char* ws = (char*)d_ws;
  const size_t MB = 1024 * 1024;
  u16* xb  = (u16*)(ws + 0 * MB);
  u16* wqb = (u16*)(ws + 8 * MB);
  u16* wkb = (u16*)(ws + 10 * MB);
  u16* wvb = (u16*)(ws + 12 * MB);
  u16* wpb = (u16*)(ws + 14 * MB);
  u16* qh  = (u16*)(ws + 16 * MB);
  u16* kh  = (u16*)(ws + 24 * MB);
  u16* vt  = (u16*)(ws + 32 * MB);
  u16* y   = (u16*)(ws + 40 * MB);
  // partial buffers reuse the region dead after gemm_qkv (xb + wqb):
  u16*   po  = (u16*)(ws + 0 * MB);    // 1024 slots x 64 rows x 64 d bf16 = 8 MB
  float* pml = (float*)(ws + 8 * MB);  // 1024 slots x 64 rows x {m,l} f32 = 0.5 MB

  cast_all<<<dim3(512, 8), dim3(256), 0, stream>>>(
      x, wq, wk, wv, wp, xb, wqb, wkb, wvb, wpb);

  gemm_qkv<<<dim3(32, 8, 3), dim3(256), 0, stream>>>(
      xb, wqb, wkb, wvb, bq, bk, bv, qh, kh, vt);

  attn_kernel<<<dim3(1536), dim3(256), 0, stream>>>(qh, kh, vt, y, po, pml);

  attn_combine<<<dim3(512), dim3(256), 0, stream>>>(po, pml, y);

  gemm_proj<<<dim3(32, 16), dim3(256), 0, stream>>>(y, wpb, bp, (float*)d_out);
}